// Round 8
// baseline (201.762 us; speedup 1.0000x reference)
//
#include <hip/hip_runtime.h>
#include <stdint.h>

#define N_ 2048
#define D_ 128
#define B_ 8
#define NT 16            // N_/128
#define NPAIRS 136       // NT*(NT+1)/2
#define NBINS 8192
#define GH 34            // hist block-groups per pair
#define TPG 4            // tiles per hist block (GH*TPG == NPAIRS)

typedef __attribute__((ext_vector_type(8))) _Float16 half8;
typedef __attribute__((ext_vector_type(4))) float f32x4;

// ws layout (bytes)
#define OFF_ACCUM 0
#define OFF_RU    256                            // 16 entries, 64B stride
#define OFF_THR   1280                           // 16 floats
#define OFF_REP   4096                           // 16*34*16384 = 8,912,896
#define OFF_F     (4096 + (size_t)16*GH*(NBINS*2))  // panels: 16 * 2048*128*2B = 8 MB
#define NEED      (OFF_F + (size_t)16*N_*D_*2)   // ~17.3 MB

// Fragment-major f16 panel: panel p (2048 rows x 128 k) as [128 rt][4 kt]
// 1KB fragments; within a fragment lane l=(r&15)+((k>>3)&3)*16 owns 16B at l*16.

// 128x128 tile (ti,tj) of X*X^T in f16 MFMA, direct-from-global fragments,
// double-buffered prefetch. 4 waves (2x2), each 64x64 = 4x4 frags of 16x16x32.
__device__ __forceinline__ void gemm16(const _Float16* __restrict__ Fp,
        int ti, int tj, f32x4 acc[4][4], int t)
{
    const int lane = t & 63;
    const int wv = t >> 6, wr = wv >> 1, wc = wv & 1;
    const _Float16* A  = Fp + (size_t)(ti*8 + wr*4)*2048 + (size_t)lane*8;
    const _Float16* Bp = Fp + (size_t)(tj*8 + wc*4)*2048 + (size_t)lane*8;

    half8 a[2][4], b[2][4];
    #pragma unroll
    for (int mm = 0; mm < 4; ++mm) {
        a[0][mm] = *(const half8*)&A[mm*2048];
        b[0][mm] = *(const half8*)&Bp[mm*2048];
    }
    #pragma unroll
    for (int mm = 0; mm < 4; ++mm)
        #pragma unroll
        for (int nn = 0; nn < 4; ++nn)
            acc[mm][nn] = f32x4{0.f, 0.f, 0.f, 0.f};

    #pragma unroll
    for (int kt = 0; kt < 4; ++kt) {
        const int cur = kt & 1, nxt = cur ^ 1;
        if (kt < 3) {
            #pragma unroll
            for (int mm = 0; mm < 4; ++mm) {
                a[nxt][mm] = *(const half8*)&A[mm*2048 + (kt+1)*512];
                b[nxt][mm] = *(const half8*)&Bp[mm*2048 + (kt+1)*512];
            }
        }
        #pragma unroll
        for (int mm = 0; mm < 4; ++mm)
            #pragma unroll
            for (int nn = 0; nn < 4; ++nn)
                acc[mm][nn] = __builtin_amdgcn_mfma_f32_16x16x32_f16(a[cur][mm], b[cur][nn], acc[mm][nn], 0, 0, 0);
    }
}

// f32 -> f16 fragment-major panels + fused per-pair max row-norm^2 (sim bound)
__global__ __launch_bounds__(256) void convert_kernel(
    const float* __restrict__ Xin, const float* __restrict__ Xtg,
    _Float16* __restrict__ F, uint32_t* __restrict__ Ru)
{
    const int t = threadIdx.x;
    const int m = blockIdx.y;
    const float* X = m ? Xtg : Xin;
    const size_t e8 = (size_t)blockIdx.x * 256 + t;
    const size_t idx = e8 * 8;
    const int b = (int)(e8 >> 15);
    const int r = (int)((idx >> 7) & 2047);
    const int k = (int)(idx & 127);

    float4 v0 = *(const float4*)&X[idx];
    float4 v1 = *(const float4*)&X[idx + 4];
    float vv[8] = {v0.x, v0.y, v0.z, v0.w, v1.x, v1.y, v1.z, v1.w};
    _Float16 h8[8];
    float s = 0.f;
    #pragma unroll
    for (int j = 0; j < 8; ++j) {
        float f = fminf(fmaxf(vv[j], -60000.f), 60000.f);  // f16-range guard
        h8[j] = (_Float16)f;
        s += vv[j] * vv[j];
    }
    const int p = m * B_ + b;
    const size_t off = (size_t)p * (N_*D_)
        + (size_t)((r >> 4) * 4 + (k >> 5)) * 512
        + (size_t)((r & 15) + ((k >> 3) & 3) * 16) * 8;
    *(half8*)&F[off] = *(half8*)h8;

    // 16 consecutive lanes cover one row of 128 k
    s += __shfl_xor(s, 1); s += __shfl_xor(s, 2); s += __shfl_xor(s, 4); s += __shfl_xor(s, 8);
    s = fmaxf(s, __shfl_xor(s, 16)); s = fmaxf(s, __shfl_xor(s, 32));
    __shared__ float wm[4];
    if ((t & 63) == 0) wm[t >> 6] = s;
    __syncthreads();
    if (t == 0) {
        float mx = fmaxf(fmaxf(wm[0], wm[1]), fmaxf(wm[2], wm[3]));
        atomicMax(&Ru[p * 16], __float_as_uint(mx));   // positive: uint order == float order
    }
}

// 8K-bin hist of POSITIVE sims over (0,R], packed-u16 LDS, 4 tiles/block,
// non-atomic replica flush. v<=0 skipped: threshold (top 10%) is far above 0,
// so rank-from-top is unaffected and the bin-0 same-address hotspot is gone.
// Low 4 bits of blockIdx carry p -> pair pinned to one XCD L2.
__global__ __launch_bounds__(256) void hist_kernel(
    const _Float16* __restrict__ F, const uint32_t* __restrict__ Ru,
    uint32_t* __restrict__ rep)
{
    __shared__ uint32_t lh[NBINS / 2];   // 16 KB packed u16 pairs
    const int t = threadIdx.x;
    const int id = blockIdx.x;
    const int p = id & 15, g = id >> 4;

    for (int i = t; i < NBINS/2; i += 256) lh[i] = 0;
    __syncthreads();

    const _Float16* Fp = F + (size_t)p * (N_*D_);
    const float R = __uint_as_float(Ru[p * 16]);
    const float scl = (float)NBINS / R;

    for (int j = 0; j < TPG; ++j) {
        int rem = g * TPG + j, ti = 0;
        while (true) { int len = NT - ti; if (rem < len) break; rem -= len; ++ti; }
        const int tj = ti + rem;
        const uint32_t w = (ti == tj) ? 1u : 2u;

        f32x4 acc[4][4];
        gemm16(Fp, ti, tj, acc, t);
        #pragma unroll
        for (int mm = 0; mm < 4; ++mm)
            #pragma unroll
            for (int nn = 0; nn < 4; ++nn)
                #pragma unroll
                for (int r = 0; r < 4; ++r) {
                    float v = acc[mm][nn][r];
                    if (v > 0.f) {
                        int bin = (int)(v * scl);
                        if (bin >= NBINS) bin = NBINS - 1;
                        atomicAdd(&lh[bin >> 1], w << ((bin & 1) * 16));
                    }
                }
    }
    __syncthreads();
    uint32_t* dst = rep + ((size_t)p * GH + g) * (NBINS/2);
    for (int i = t; i < NBINS/2; i += 256) dst[i] = lh[i];
}

// sum GH replicas -> full u32 hist in LDS -> descending scan -> thr[p]
__global__ __launch_bounds__(256) void reduce_select(
    const uint32_t* __restrict__ rep, const int* __restrict__ kptr,
    const uint32_t* __restrict__ Ru, float* __restrict__ thr)
{
    __shared__ uint32_t h[NBINS];        // 32 KB
    __shared__ uint32_t csum[256], cpre[256];
    const int p = blockIdx.x, t = threadIdx.x;
    const uint32_t* base = rep + (size_t)p * GH * (NBINS/2);

    for (int j = 0; j < NBINS/2/256; ++j) {   // 4096 words / 256 threads
        const int wd = j * 256 + t;
        uint32_t lo = 0, hi = 0;
        #pragma unroll
        for (int g = 0; g < GH; ++g) {
            uint32_t x = base[(size_t)g * (NBINS/2) + wd];
            lo += x & 0xffffu; hi += x >> 16;
        }
        h[wd*2] = lo; h[wd*2 + 1] = hi;
    }
    __syncthreads();

    const uint32_t k0 = (uint32_t)kptr[0];
    const float R = __uint_as_float(Ru[p * 16]);
    const float binw = R / (float)NBINS;

    const int top = NBINS - 1 - t * 32;
    uint32_t s = 0;
    #pragma unroll
    for (int j = 0; j < 32; ++j) s += h[top - j];
    csum[t] = s;
    __syncthreads();
    if (t == 0) { uint32_t run = 0; for (int i = 0; i < 256; ++i) { cpre[i] = run; run += csum[i]; } }
    __syncthreads();
    const uint32_t above = cpre[t];
    if (above < k0 && above + s >= k0) {
        uint32_t cum = above;
        for (int j = 0; j < 32; ++j) {
            int bin = top - j;
            cum += h[bin];
            if (cum >= k0) { thr[p] = (float)bin * binw; break; }   // lower edge
        }
    }
}

// masked MSE: f16 gemms for both matrices, squared diff -> double atomic.
// Low 3 bits of blockIdx carry p -> pair-group (2 panels = 2MB) on one XCD.
__global__ __launch_bounds__(256) void mse_kernel(
    const _Float16* __restrict__ F, const float* __restrict__ thr,
    double* __restrict__ accum)
{
    const int t = threadIdx.x;
    const int id = blockIdx.x;
    const int p = id & 7, tile = id >> 3;

    int rem = tile, ti = 0;
    while (true) { int len = NT - ti; if (rem < len) break; rem -= len; ++ti; }
    const int tj = ti + rem;
    const uint32_t w = (ti == tj) ? 1u : 2u;

    f32x4 acc[4][4], accT[4][4];
    gemm16(F + (size_t)p * (N_*D_),        ti, tj, acc,  t);
    gemm16(F + (size_t)(B_ + p) * (N_*D_), ti, tj, accT, t);

    const float thrI = thr[p], thrT = thr[B_ + p];
    float local = 0.f;
    #pragma unroll
    for (int mm = 0; mm < 4; ++mm)
        #pragma unroll
        for (int nn = 0; nn < 4; ++nn)
            #pragma unroll
            for (int r = 0; r < 4; ++r) {
                float vI = acc[mm][nn][r],  aI = (vI >= thrI) ? vI : 0.f;
                float vT = accT[mm][nn][r], aT = (vT >= thrT) ? vT : 0.f;
                float d = aI - aT;
                local += d * d;
            }
    local *= (float)w;
    #pragma unroll
    for (int off = 32; off; off >>= 1) local += __shfl_down(local, off);
    __shared__ float wsum[4];
    if ((t & 63) == 0) wsum[t >> 6] = local;
    __syncthreads();
    if (t == 0) {
        double s2 = (double)wsum[0] + (double)wsum[1] + (double)wsum[2] + (double)wsum[3];
        atomicAdd(accum, s2);
    }
}

__global__ void finalize_kernel(const double* __restrict__ accum, float* __restrict__ out) {
    out[0] = (float)(accum[0] / ((double)B_ * (double)N_ * (double)N_));
}

extern "C" void kernel_launch(void* const* d_in, const int* in_sizes, int n_in,
                              void* d_out, int out_size, void* d_ws, size_t ws_size,
                              hipStream_t stream)
{
    const float* Xin = (const float*)d_in[0];
    const float* Xtg = (const float*)d_in[1];
    const int*  kptr = (const int*)d_in[3];
    float* out = (float*)d_out;

    char* ws = (char*)d_ws;
    double*    accum = (double*)   (ws + OFF_ACCUM);
    uint32_t*  Ru    = (uint32_t*) (ws + OFF_RU);
    float*     thr   = (float*)    (ws + OFF_THR);
    uint32_t*  rep   = (uint32_t*) (ws + OFF_REP);
    _Float16*  F     = (_Float16*) (ws + OFF_F);
    if (ws_size < NEED) return;

    hipMemsetAsync(d_ws, 0, OFF_REP, stream);   // accum, Ru, thr (replicas/F overwritten)

    dim3 blk(256);
    convert_kernel<<<dim3(1024, 2), blk, 0, stream>>>(Xin, Xtg, F, Ru);
    hist_kernel<<<dim3(GH * 16), blk, 0, stream>>>(F, Ru, rep);
    reduce_select<<<dim3(16), blk, 0, stream>>>(rep, kptr, Ru, thr);
    mse_kernel<<<dim3(NPAIRS * 8), blk, 0, stream>>>(F, thr, accum);
    finalize_kernel<<<1, 1, 0, stream>>>(accum, out);
}

// Round 9
// 89.918 us; speedup vs baseline: 2.2439x; 2.2439x over previous
//
#include <hip/hip_runtime.h>
#include <stdint.h>

#define N_ 2048
#define D_ 128
#define B_ 8
#define NT 16            // N_/128
#define NPAIRS 136       // NT*(NT+1)/2
#define NBINS 8192
#define GH 34            // hist block-groups per pair
#define TPG 4            // tiles per hist block (GH*TPG == NPAIRS)

typedef __attribute__((ext_vector_type(8))) _Float16 half8;
typedef __attribute__((ext_vector_type(4))) float f32x4;

// ws layout (bytes)
#define OFF_ACCUM 0
#define OFF_RU    256                               // 16 entries, 64B stride
#define OFF_THR   1280                              // 16 floats
#define OFF_H32   4096                              // 16*8192*4 = 512 KB
#define OFF_REP   (4096 + (size_t)16*NBINS*4)       // 16*34*16384 = 8,912,896
#define OFF_F     (OFF_REP + (size_t)16*GH*(NBINS*2))
#define NEED      (OFF_F + (size_t)16*N_*D_*2)      // ~17.8 MB

// Fragment-major f16 panel: panel p (2048 rows x 128 k) as [128 rt][4 kt]
// 1KB fragments; within a fragment lane l=(r&15)+((k>>3)&3)*16 owns 16B at l*16.

// 128x128 tile (ti,tj) of X*X^T in f16 MFMA, direct-from-global fragments,
// double-buffered prefetch. 4 waves (2x2), each 64x64 = 4x4 frags of 16x16x32.
__device__ __forceinline__ void gemm16(const _Float16* __restrict__ Fp,
        int ti, int tj, f32x4 acc[4][4], int t)
{
    const int lane = t & 63;
    const int wv = t >> 6, wr = wv >> 1, wc = wv & 1;
    const _Float16* A  = Fp + (size_t)(ti*8 + wr*4)*2048 + (size_t)lane*8;
    const _Float16* Bp = Fp + (size_t)(tj*8 + wc*4)*2048 + (size_t)lane*8;

    half8 a[2][4], b[2][4];
    #pragma unroll
    for (int mm = 0; mm < 4; ++mm) {
        a[0][mm] = *(const half8*)&A[mm*2048];
        b[0][mm] = *(const half8*)&Bp[mm*2048];
    }
    #pragma unroll
    for (int mm = 0; mm < 4; ++mm)
        #pragma unroll
        for (int nn = 0; nn < 4; ++nn)
            acc[mm][nn] = f32x4{0.f, 0.f, 0.f, 0.f};

    #pragma unroll
    for (int kt = 0; kt < 4; ++kt) {
        const int cur = kt & 1, nxt = cur ^ 1;
        if (kt < 3) {
            #pragma unroll
            for (int mm = 0; mm < 4; ++mm) {
                a[nxt][mm] = *(const half8*)&A[mm*2048 + (kt+1)*512];
                b[nxt][mm] = *(const half8*)&Bp[mm*2048 + (kt+1)*512];
            }
        }
        #pragma unroll
        for (int mm = 0; mm < 4; ++mm)
            #pragma unroll
            for (int nn = 0; nn < 4; ++nn)
                acc[mm][nn] = __builtin_amdgcn_mfma_f32_16x16x32_f16(a[cur][mm], b[cur][nn], acc[mm][nn], 0, 0, 0);
    }
}

// f32 -> f16 fragment-major panels + fused per-pair max row-norm^2 (sim bound)
__global__ __launch_bounds__(256) void convert_kernel(
    const float* __restrict__ Xin, const float* __restrict__ Xtg,
    _Float16* __restrict__ F, uint32_t* __restrict__ Ru)
{
    const int t = threadIdx.x;
    const int m = blockIdx.y;
    const float* X = m ? Xtg : Xin;
    const size_t e8 = (size_t)blockIdx.x * 256 + t;
    const size_t idx = e8 * 8;
    const int b = (int)(e8 >> 15);
    const int r = (int)((idx >> 7) & 2047);
    const int k = (int)(idx & 127);

    float4 v0 = *(const float4*)&X[idx];
    float4 v1 = *(const float4*)&X[idx + 4];
    float vv[8] = {v0.x, v0.y, v0.z, v0.w, v1.x, v1.y, v1.z, v1.w};
    _Float16 h8[8];
    float s = 0.f;
    #pragma unroll
    for (int j = 0; j < 8; ++j) {
        float f = fminf(fmaxf(vv[j], -60000.f), 60000.f);  // f16-range guard
        h8[j] = (_Float16)f;
        s += vv[j] * vv[j];
    }
    const int p = m * B_ + b;
    const size_t off = (size_t)p * (N_*D_)
        + (size_t)((r >> 4) * 4 + (k >> 5)) * 512
        + (size_t)((r & 15) + ((k >> 3) & 3) * 16) * 8;
    *(half8*)&F[off] = *(half8*)h8;

    // 16 consecutive lanes cover one row of 128 k
    s += __shfl_xor(s, 1); s += __shfl_xor(s, 2); s += __shfl_xor(s, 4); s += __shfl_xor(s, 8);
    s = fmaxf(s, __shfl_xor(s, 16)); s = fmaxf(s, __shfl_xor(s, 32));
    __shared__ float wm[4];
    if ((t & 63) == 0) wm[t >> 6] = s;
    __syncthreads();
    if (t == 0) {
        float mx = fmaxf(fmaxf(wm[0], wm[1]), fmaxf(wm[2], wm[3]));
        atomicMax(&Ru[p * 16], __float_as_uint(mx));   // positive: uint order == float order
    }
}

// 8K-bin hist of POSITIVE sims over (0,R], packed-u16 LDS, 4 tiles/block,
// non-atomic replica flush. v<=0 skipped (threshold is far above 0).
// Low 4 bits of blockIdx carry p -> pair pinned to one XCD L2.
__global__ __launch_bounds__(256) void hist_kernel(
    const _Float16* __restrict__ F, const uint32_t* __restrict__ Ru,
    uint32_t* __restrict__ rep)
{
    __shared__ uint32_t lh[NBINS / 2];   // 16 KB packed u16 pairs
    const int t = threadIdx.x;
    const int id = blockIdx.x;
    const int p = id & 15, g = id >> 4;

    for (int i = t; i < NBINS/2; i += 256) lh[i] = 0;
    __syncthreads();

    const _Float16* Fp = F + (size_t)p * (N_*D_);
    const float R = __uint_as_float(Ru[p * 16]);
    const float scl = (float)NBINS / R;

    for (int j = 0; j < TPG; ++j) {
        int rem = g * TPG + j, ti = 0;
        while (true) { int len = NT - ti; if (rem < len) break; rem -= len; ++ti; }
        const int tj = ti + rem;
        const uint32_t w = (ti == tj) ? 1u : 2u;

        f32x4 acc[4][4];
        gemm16(Fp, ti, tj, acc, t);
        #pragma unroll
        for (int mm = 0; mm < 4; ++mm)
            #pragma unroll
            for (int nn = 0; nn < 4; ++nn)
                #pragma unroll
                for (int r = 0; r < 4; ++r) {
                    float v = acc[mm][nn][r];
                    if (v > 0.f) {
                        int bin = (int)(v * scl);
                        if (bin >= NBINS) bin = NBINS - 1;
                        atomicAdd(&lh[bin >> 1], w << ((bin & 1) * 16));
                    }
                }
    }
    __syncthreads();
    uint32_t* dst = rep + ((size_t)p * GH + g) * (NBINS/2);
    for (int i = t; i < NBINS/2; i += 256) dst[i] = lh[i];
}

// parallel replica reduce: 256 blocks (16 pairs x 16 chunks), coalesced.
__global__ __launch_bounds__(256) void reduce_kernel(
    const uint32_t* __restrict__ rep, uint32_t* __restrict__ h32)
{
    const int id = blockIdx.x;
    const int p = id & 15, chunk = id >> 4;
    const int t = threadIdx.x;
    const int wd = chunk * 256 + t;                 // packed-word idx 0..4095
    const uint32_t* base = rep + (size_t)p * GH * (NBINS/2) + wd;
    uint32_t lo = 0, hi = 0;
    #pragma unroll
    for (int g = 0; g < GH; ++g) {
        uint32_t x = base[(size_t)g * (NBINS/2)];
        lo += x & 0xffffu; hi += x >> 16;
    }
    uint32_t* hp = h32 + (size_t)p * NBINS;
    hp[wd*2]     = lo;
    hp[wd*2 + 1] = hi;
}

// descending scan of u32 hist: thr = lower edge of bin holding rank k
__global__ __launch_bounds__(256) void select_kernel(
    const uint32_t* __restrict__ h32, const int* __restrict__ kptr,
    const uint32_t* __restrict__ Ru, float* __restrict__ thr)
{
    __shared__ uint32_t csum[256], cpre[256];
    const int p = blockIdx.x, t = threadIdx.x;
    const uint32_t* h = h32 + (size_t)p * NBINS;
    const uint32_t k0 = (uint32_t)kptr[0];
    const float R = __uint_as_float(Ru[p * 16]);
    const float binw = R / (float)NBINS;

    const int top = NBINS - 1 - t * 32;
    uint32_t s = 0;
    #pragma unroll
    for (int j = 0; j < 32; ++j) s += h[top - j];
    csum[t] = s;
    __syncthreads();
    if (t == 0) { uint32_t run = 0; for (int i = 0; i < 256; ++i) { cpre[i] = run; run += csum[i]; } }
    __syncthreads();
    const uint32_t above = cpre[t];
    if (above < k0 && above + s >= k0) {
        uint32_t cum = above;
        for (int j = 0; j < 32; ++j) {
            int bin = top - j;
            cum += h[bin];
            if (cum >= k0) { thr[p] = (float)bin * binw; break; }   // lower edge
        }
    }
}

// masked MSE: f16 gemms for both matrices, squared diff -> double atomic.
// Low 3 bits of blockIdx carry p -> pair-group (2 panels = 2MB) on one XCD.
__global__ __launch_bounds__(256) void mse_kernel(
    const _Float16* __restrict__ F, const float* __restrict__ thr,
    double* __restrict__ accum)
{
    const int t = threadIdx.x;
    const int id = blockIdx.x;
    const int p = id & 7, tile = id >> 3;

    int rem = tile, ti = 0;
    while (true) { int len = NT - ti; if (rem < len) break; rem -= len; ++ti; }
    const int tj = ti + rem;
    const uint32_t w = (ti == tj) ? 1u : 2u;

    f32x4 acc[4][4], accT[4][4];
    gemm16(F + (size_t)p * (N_*D_),        ti, tj, acc,  t);
    gemm16(F + (size_t)(B_ + p) * (N_*D_), ti, tj, accT, t);

    const float thrI = thr[p], thrT = thr[B_ + p];
    float local = 0.f;
    #pragma unroll
    for (int mm = 0; mm < 4; ++mm)
        #pragma unroll
        for (int nn = 0; nn < 4; ++nn)
            #pragma unroll
            for (int r = 0; r < 4; ++r) {
                float vI = acc[mm][nn][r],  aI = (vI >= thrI) ? vI : 0.f;
                float vT = accT[mm][nn][r], aT = (vT >= thrT) ? vT : 0.f;
                float d = aI - aT;
                local += d * d;
            }
    local *= (float)w;
    #pragma unroll
    for (int off = 32; off; off >>= 1) local += __shfl_down(local, off);
    __shared__ float wsum[4];
    if ((t & 63) == 0) wsum[t >> 6] = local;
    __syncthreads();
    if (t == 0) {
        double s2 = (double)wsum[0] + (double)wsum[1] + (double)wsum[2] + (double)wsum[3];
        atomicAdd(accum, s2);
    }
}

__global__ void finalize_kernel(const double* __restrict__ accum, float* __restrict__ out) {
    out[0] = (float)(accum[0] / ((double)B_ * (double)N_ * (double)N_));
}

extern "C" void kernel_launch(void* const* d_in, const int* in_sizes, int n_in,
                              void* d_out, int out_size, void* d_ws, size_t ws_size,
                              hipStream_t stream)
{
    const float* Xin = (const float*)d_in[0];
    const float* Xtg = (const float*)d_in[1];
    const int*  kptr = (const int*)d_in[3];
    float* out = (float*)d_out;

    char* ws = (char*)d_ws;
    double*    accum = (double*)   (ws + OFF_ACCUM);
    uint32_t*  Ru    = (uint32_t*) (ws + OFF_RU);
    float*     thr   = (float*)    (ws + OFF_THR);
    uint32_t*  h32   = (uint32_t*) (ws + OFF_H32);
    uint32_t*  rep   = (uint32_t*) (ws + OFF_REP);
    _Float16*  F     = (_Float16*) (ws + OFF_F);
    if (ws_size < NEED) return;

    hipMemsetAsync(d_ws, 0, OFF_H32, stream);   // accum, Ru, thr (h32/rep/F overwritten)

    dim3 blk(256);
    convert_kernel<<<dim3(1024, 2), blk, 0, stream>>>(Xin, Xtg, F, Ru);
    hist_kernel<<<dim3(GH * 16), blk, 0, stream>>>(F, Ru, rep);
    reduce_kernel<<<dim3(16 * 16), blk, 0, stream>>>(rep, h32);
    select_kernel<<<dim3(16), blk, 0, stream>>>(h32, kptr, Ru, thr);
    mse_kernel<<<dim3(NPAIRS * 8), blk, 0, stream>>>(F, thr, accum);
    finalize_kernel<<<1, 1, 0, stream>>>(accum, out);
}

// Round 10
// 64.700 us; speedup vs baseline: 3.1184x; 1.3898x over previous
//
#include <hip/hip_runtime.h>
#include <stdint.h>

#define N_ 2048
#define D_ 128
#define B_ 8
#define NT 16            // N_/128
#define NPAIRS 136       // NT*(NT+1)/2
#define NBINS 8192
#define GH 34            // hist block-groups per pair
#define TPG 4            // tiles per hist block (GH*TPG == NPAIRS)

typedef __attribute__((ext_vector_type(8))) _Float16 half8;
typedef __attribute__((ext_vector_type(4))) float f32x4;

// ws layout (bytes)
#define OFF_ACCUM 0
#define OFF_RU    256                               // 16 entries, 64B stride
#define OFF_THR   1280                              // 16 floats
#define OFF_H32   4096                              // 16*8192*4 = 512 KB
#define OFF_REP   (4096 + (size_t)16*NBINS*4)       // 16*34*16384 = 8,912,896
#define OFF_F     (OFF_REP + (size_t)16*GH*(NBINS*2))
#define NEED      (OFF_F + (size_t)16*N_*D_*2)      // ~17.8 MB

// Fragment-major f16 panel: panel p (2048 rows x 128 k) as [128 rt][4 kt]
// 1KB fragments; within a fragment lane l=(r&15)+((k>>3)&3)*16 owns 16B at l*16.

// Full 128x128 tile (ti,tj) of X*X^T, f16 MFMA, direct-from-global fragments,
// double-buffered prefetch. 4 waves (2x2), each 64x64 = 4x4 frags of 16x16x32.
__device__ __forceinline__ void gemm16(const _Float16* __restrict__ Fp,
        int ti, int tj, f32x4 acc[4][4], int t)
{
    const int lane = t & 63;
    const int wv = t >> 6, wr = wv >> 1, wc = wv & 1;
    const _Float16* A  = Fp + (size_t)(ti*8 + wr*4)*2048 + (size_t)lane*8;
    const _Float16* Bp = Fp + (size_t)(tj*8 + wc*4)*2048 + (size_t)lane*8;

    half8 a[2][4], b[2][4];
    #pragma unroll
    for (int mm = 0; mm < 4; ++mm) {
        a[0][mm] = *(const half8*)&A[mm*2048];
        b[0][mm] = *(const half8*)&Bp[mm*2048];
    }
    #pragma unroll
    for (int mm = 0; mm < 4; ++mm)
        #pragma unroll
        for (int nn = 0; nn < 4; ++nn)
            acc[mm][nn] = f32x4{0.f, 0.f, 0.f, 0.f};

    #pragma unroll
    for (int kt = 0; kt < 4; ++kt) {
        const int cur = kt & 1, nxt = cur ^ 1;
        if (kt < 3) {
            #pragma unroll
            for (int mm = 0; mm < 4; ++mm) {
                a[nxt][mm] = *(const half8*)&A[mm*2048 + (kt+1)*512];
                b[nxt][mm] = *(const half8*)&Bp[mm*2048 + (kt+1)*512];
            }
        }
        #pragma unroll
        for (int mm = 0; mm < 4; ++mm)
            #pragma unroll
            for (int nn = 0; nn < 4; ++nn)
                acc[mm][nn] = __builtin_amdgcn_mfma_f32_16x16x32_f16(a[cur][mm], b[cur][nn], acc[mm][nn], 0, 0, 0);
    }
}

// Quarter tile: only fragment-row mm=0 per wave -> rows (r mod 64)<16,
// all 128 cols. 16 MFMA instead of 64, A-loads 1/4. For hist sampling.
__device__ __forceinline__ void gemm16_q(const _Float16* __restrict__ Fp,
        int ti, int tj, f32x4 acc[4], int t)
{
    const int lane = t & 63;
    const int wv = t >> 6, wr = wv >> 1, wc = wv & 1;
    const _Float16* A  = Fp + (size_t)(ti*8 + wr*4)*2048 + (size_t)lane*8;
    const _Float16* Bp = Fp + (size_t)(tj*8 + wc*4)*2048 + (size_t)lane*8;

    half8 a[2], b[2][4];
    a[0] = *(const half8*)&A[0];
    #pragma unroll
    for (int nn = 0; nn < 4; ++nn) b[0][nn] = *(const half8*)&Bp[nn*2048];
    #pragma unroll
    for (int nn = 0; nn < 4; ++nn) acc[nn] = f32x4{0.f, 0.f, 0.f, 0.f};

    #pragma unroll
    for (int kt = 0; kt < 4; ++kt) {
        const int cur = kt & 1, nxt = cur ^ 1;
        if (kt < 3) {
            a[nxt] = *(const half8*)&A[(kt+1)*512];
            #pragma unroll
            for (int nn = 0; nn < 4; ++nn)
                b[nxt][nn] = *(const half8*)&Bp[nn*2048 + (kt+1)*512];
        }
        #pragma unroll
        for (int nn = 0; nn < 4; ++nn)
            acc[nn] = __builtin_amdgcn_mfma_f32_16x16x32_f16(a[cur], b[cur][nn], acc[nn], 0, 0, 0);
    }
}

// f32 -> f16 fragment-major panels + fused per-pair max row-norm^2 (sim bound)
__global__ __launch_bounds__(256) void convert_kernel(
    const float* __restrict__ Xin, const float* __restrict__ Xtg,
    _Float16* __restrict__ F, uint32_t* __restrict__ Ru)
{
    const int t = threadIdx.x;
    const int m = blockIdx.y;
    const float* X = m ? Xtg : Xin;
    const size_t e8 = (size_t)blockIdx.x * 256 + t;
    const size_t idx = e8 * 8;
    const int b = (int)(e8 >> 15);
    const int r = (int)((idx >> 7) & 2047);
    const int k = (int)(idx & 127);

    float4 v0 = *(const float4*)&X[idx];
    float4 v1 = *(const float4*)&X[idx + 4];
    float vv[8] = {v0.x, v0.y, v0.z, v0.w, v1.x, v1.y, v1.z, v1.w};
    _Float16 h8[8];
    float s = 0.f;
    #pragma unroll
    for (int j = 0; j < 8; ++j) {
        float f = fminf(fmaxf(vv[j], -60000.f), 60000.f);  // f16-range guard
        h8[j] = (_Float16)f;
        s += vv[j] * vv[j];
    }
    const int p = m * B_ + b;
    const size_t off = (size_t)p * (N_*D_)
        + (size_t)((r >> 4) * 4 + (k >> 5)) * 512
        + (size_t)((r & 15) + ((k >> 3) & 3) * 16) * 8;
    *(half8*)&F[off] = *(half8*)h8;

    // 16 consecutive lanes cover one row of 128 k
    s += __shfl_xor(s, 1); s += __shfl_xor(s, 2); s += __shfl_xor(s, 4); s += __shfl_xor(s, 8);
    s = fmaxf(s, __shfl_xor(s, 16)); s = fmaxf(s, __shfl_xor(s, 32));
    __shared__ float wm[4];
    if ((t & 63) == 0) wm[t >> 6] = s;
    __syncthreads();
    if (t == 0) {
        float mx = fmaxf(fmaxf(wm[0], wm[1]), fmaxf(wm[2], wm[3]));
        atomicMax(&Ru[p * 16], __float_as_uint(mx));   // positive: uint order == float order
    }
}

// Sampled 8K-bin hist of POSITIVE sims over (0,R]: quarter-tile GEMM
// (rows (r mod 64)<16 — deterministic 1/4 sample; select uses k/4).
// Packed-u16 LDS, non-atomic replica flush. v<=0 skipped.
// Low 4 bits of blockIdx carry p -> pair pinned to one XCD L2.
__global__ __launch_bounds__(256) void hist_kernel(
    const _Float16* __restrict__ F, const uint32_t* __restrict__ Ru,
    uint32_t* __restrict__ rep)
{
    __shared__ uint32_t lh[NBINS / 2];   // 16 KB packed u16 pairs
    const int t = threadIdx.x;
    const int id = blockIdx.x;
    const int p = id & 15, g = id >> 4;

    for (int i = t; i < NBINS/2; i += 256) lh[i] = 0;
    __syncthreads();

    const _Float16* Fp = F + (size_t)p * (N_*D_);
    const float R = __uint_as_float(Ru[p * 16]);
    const float scl = (float)NBINS / R;

    for (int j = 0; j < TPG; ++j) {
        int rem = g * TPG + j, ti = 0;
        while (true) { int len = NT - ti; if (rem < len) break; rem -= len; ++ti; }
        const int tj = ti + rem;
        const uint32_t w = (ti == tj) ? 1u : 2u;

        f32x4 acc[4];
        gemm16_q(Fp, ti, tj, acc, t);
        #pragma unroll
        for (int nn = 0; nn < 4; ++nn)
            #pragma unroll
            for (int r = 0; r < 4; ++r) {
                float v = acc[nn][r];
                if (v > 0.f) {
                    int bin = (int)(v * scl);
                    if (bin >= NBINS) bin = NBINS - 1;
                    atomicAdd(&lh[bin >> 1], w << ((bin & 1) * 16));
                }
            }
    }
    __syncthreads();
    uint32_t* dst = rep + ((size_t)p * GH + g) * (NBINS/2);
    for (int i = t; i < NBINS/2; i += 256) dst[i] = lh[i];
}

// parallel replica reduce: 256 blocks (16 pairs x 16 chunks), coalesced.
__global__ __launch_bounds__(256) void reduce_kernel(
    const uint32_t* __restrict__ rep, uint32_t* __restrict__ h32)
{
    const int id = blockIdx.x;
    const int p = id & 15, chunk = id >> 4;
    const int t = threadIdx.x;
    const int wd = chunk * 256 + t;                 // packed-word idx 0..4095
    const uint32_t* base = rep + (size_t)p * GH * (NBINS/2) + wd;
    uint32_t lo = 0, hi = 0;
    #pragma unroll
    for (int g = 0; g < GH; ++g) {
        uint32_t x = base[(size_t)g * (NBINS/2)];
        lo += x & 0xffffu; hi += x >> 16;
    }
    uint32_t* hp = h32 + (size_t)p * NBINS;
    hp[wd*2]     = lo;
    hp[wd*2 + 1] = hi;
}

// descending scan of u32 hist with rank k/4 (1/4 sample): thr = bin lower edge
__global__ __launch_bounds__(256) void select_kernel(
    const uint32_t* __restrict__ h32, const int* __restrict__ kptr,
    const uint32_t* __restrict__ Ru, float* __restrict__ thr)
{
    __shared__ uint32_t csum[256], cpre[256];
    const int p = blockIdx.x, t = threadIdx.x;
    const uint32_t* h = h32 + (size_t)p * NBINS;
    const uint32_t k0 = ((uint32_t)kptr[0] + 2u) >> 2;   // sampled rank
    const float R = __uint_as_float(Ru[p * 16]);
    const float binw = R / (float)NBINS;

    const int top = NBINS - 1 - t * 32;
    uint32_t s = 0;
    #pragma unroll
    for (int j = 0; j < 32; ++j) s += h[top - j];
    csum[t] = s;
    __syncthreads();
    if (t == 0) { uint32_t run = 0; for (int i = 0; i < 256; ++i) { cpre[i] = run; run += csum[i]; } }
    __syncthreads();
    const uint32_t above = cpre[t];
    if (above < k0 && above + s >= k0) {
        uint32_t cum = above;
        for (int j = 0; j < 32; ++j) {
            int bin = top - j;
            cum += h[bin];
            if (cum >= k0) { thr[p] = (float)bin * binw; break; }   // lower edge
        }
    }
}

// masked MSE: full-precision f16 gemms for both matrices -> double atomic.
// Low 3 bits of blockIdx carry p -> pair-group (2 panels = 2MB) on one XCD.
__global__ __launch_bounds__(256) void mse_kernel(
    const _Float16* __restrict__ F, const float* __restrict__ thr,
    double* __restrict__ accum)
{
    const int t = threadIdx.x;
    const int id = blockIdx.x;
    const int p = id & 7, tile = id >> 3;

    int rem = tile, ti = 0;
    while (true) { int len = NT - ti; if (rem < len) break; rem -= len; ++ti; }
    const int tj = ti + rem;
    const uint32_t w = (ti == tj) ? 1u : 2u;

    f32x4 acc[4][4], accT[4][4];
    gemm16(F + (size_t)p * (N_*D_),        ti, tj, acc,  t);
    gemm16(F + (size_t)(B_ + p) * (N_*D_), ti, tj, accT, t);

    const float thrI = thr[p], thrT = thr[B_ + p];
    float local = 0.f;
    #pragma unroll
    for (int mm = 0; mm < 4; ++mm)
        #pragma unroll
        for (int nn = 0; nn < 4; ++nn)
            #pragma unroll
            for (int r = 0; r < 4; ++r) {
                float vI = acc[mm][nn][r],  aI = (vI >= thrI) ? vI : 0.f;
                float vT = accT[mm][nn][r], aT = (vT >= thrT) ? vT : 0.f;
                float d = aI - aT;
                local += d * d;
            }
    local *= (float)w;
    #pragma unroll
    for (int off = 32; off; off >>= 1) local += __shfl_down(local, off);
    __shared__ float wsum[4];
    if ((t & 63) == 0) wsum[t >> 6] = local;
    __syncthreads();
    if (t == 0) {
        double s2 = (double)wsum[0] + (double)wsum[1] + (double)wsum[2] + (double)wsum[3];
        atomicAdd(accum, s2);
    }
}

__global__ void finalize_kernel(const double* __restrict__ accum, float* __restrict__ out) {
    out[0] = (float)(accum[0] / ((double)B_ * (double)N_ * (double)N_));
}

extern "C" void kernel_launch(void* const* d_in, const int* in_sizes, int n_in,
                              void* d_out, int out_size, void* d_ws, size_t ws_size,
                              hipStream_t stream)
{
    const float* Xin = (const float*)d_in[0];
    const float* Xtg = (const float*)d_in[1];
    const int*  kptr = (const int*)d_in[3];
    float* out = (float*)d_out;

    char* ws = (char*)d_ws;
    double*    accum = (double*)   (ws + OFF_ACCUM);
    uint32_t*  Ru    = (uint32_t*) (ws + OFF_RU);
    float*     thr   = (float*)    (ws + OFF_THR);
    uint32_t*  h32   = (uint32_t*) (ws + OFF_H32);
    uint32_t*  rep   = (uint32_t*) (ws + OFF_REP);
    _Float16*  F     = (_Float16*) (ws + OFF_F);
    if (ws_size < NEED) return;

    hipMemsetAsync(d_ws, 0, OFF_H32, stream);   // accum, Ru, thr (h32/rep/F overwritten)

    dim3 blk(256);
    convert_kernel<<<dim3(1024, 2), blk, 0, stream>>>(Xin, Xtg, F, Ru);
    hist_kernel<<<dim3(GH * 16), blk, 0, stream>>>(F, Ru, rep);
    reduce_kernel<<<dim3(16 * 16), blk, 0, stream>>>(rep, h32);
    select_kernel<<<dim3(16), blk, 0, stream>>>(h32, kptr, Ru, thr);
    mse_kernel<<<dim3(NPAIRS * 8), blk, 0, stream>>>(F, thr, accum);
    finalize_kernel<<<1, 1, 0, stream>>>(accum, out);
}

// Round 11
// 61.946 us; speedup vs baseline: 3.2571x; 1.0445x over previous
//
#include <hip/hip_runtime.h>
#include <stdint.h>

#define N_ 2048
#define D_ 128
#define B_ 8
#define NT 16            // N_/128
#define NPAIRS 136       // NT*(NT+1)/2
#define NBINS 8192
#define GH 34            // hist block-groups per pair
#define TPG 4            // tiles per hist block (GH*TPG == NPAIRS)

typedef __attribute__((ext_vector_type(8))) _Float16 half8;
typedef __attribute__((ext_vector_type(4))) float f32x4;

// ws layout (bytes)
#define OFF_ACCUM 0
#define OFF_RU    256                               // 16 entries, 64B stride
#define OFF_THR   1280                              // 16 floats
#define OFF_H32   4096                              // 16*8192*4 = 512 KB
#define OFF_REP   (4096 + (size_t)16*NBINS*4)       // 16*34*16384 = 8,912,896
#define OFF_F     (OFF_REP + (size_t)16*GH*(NBINS*2))
#define NEED      (OFF_F + (size_t)16*N_*D_*2)      // ~17.8 MB

// Fragment-major f16 panel: panel p (2048 rows x 128 k) as [128 rt][4 kt]
// 1KB fragments; within a fragment lane l=(r&15)+((k>>3)&3)*16 owns 16B at l*16.

// Full 128x128 tile (ti,tj) of X*X^T, f16 MFMA, direct-from-global fragments,
// double-buffered prefetch. 4 waves (2x2), each 64x64 = 4x4 frags of 16x16x32.
__device__ __forceinline__ void gemm16(const _Float16* __restrict__ Fp,
        int ti, int tj, f32x4 acc[4][4], int t)
{
    const int lane = t & 63;
    const int wv = t >> 6, wr = wv >> 1, wc = wv & 1;
    const _Float16* A  = Fp + (size_t)(ti*8 + wr*4)*2048 + (size_t)lane*8;
    const _Float16* Bp = Fp + (size_t)(tj*8 + wc*4)*2048 + (size_t)lane*8;

    half8 a[2][4], b[2][4];
    #pragma unroll
    for (int mm = 0; mm < 4; ++mm) {
        a[0][mm] = *(const half8*)&A[mm*2048];
        b[0][mm] = *(const half8*)&Bp[mm*2048];
    }
    #pragma unroll
    for (int mm = 0; mm < 4; ++mm)
        #pragma unroll
        for (int nn = 0; nn < 4; ++nn)
            acc[mm][nn] = f32x4{0.f, 0.f, 0.f, 0.f};

    #pragma unroll
    for (int kt = 0; kt < 4; ++kt) {
        const int cur = kt & 1, nxt = cur ^ 1;
        if (kt < 3) {
            #pragma unroll
            for (int mm = 0; mm < 4; ++mm) {
                a[nxt][mm] = *(const half8*)&A[mm*2048 + (kt+1)*512];
                b[nxt][mm] = *(const half8*)&Bp[mm*2048 + (kt+1)*512];
            }
        }
        #pragma unroll
        for (int mm = 0; mm < 4; ++mm)
            #pragma unroll
            for (int nn = 0; nn < 4; ++nn)
                acc[mm][nn] = __builtin_amdgcn_mfma_f32_16x16x32_f16(a[cur][mm], b[cur][nn], acc[mm][nn], 0, 0, 0);
    }
}

// Eighth tile: fragment-row mm=0, fragment-cols nn<2 per wave ->
// rows (r mod 64)<16, cols (c mod 64)<32. 8 MFMA instead of 64.
__device__ __forceinline__ void gemm16_e(const _Float16* __restrict__ Fp,
        int ti, int tj, f32x4 acc[2], int t)
{
    const int lane = t & 63;
    const int wv = t >> 6, wr = wv >> 1, wc = wv & 1;
    const _Float16* A  = Fp + (size_t)(ti*8 + wr*4)*2048 + (size_t)lane*8;
    const _Float16* Bp = Fp + (size_t)(tj*8 + wc*4)*2048 + (size_t)lane*8;

    half8 a[2], b[2][2];
    a[0] = *(const half8*)&A[0];
    #pragma unroll
    for (int nn = 0; nn < 2; ++nn) b[0][nn] = *(const half8*)&Bp[nn*2048];
    #pragma unroll
    for (int nn = 0; nn < 2; ++nn) acc[nn] = f32x4{0.f, 0.f, 0.f, 0.f};

    #pragma unroll
    for (int kt = 0; kt < 4; ++kt) {
        const int cur = kt & 1, nxt = cur ^ 1;
        if (kt < 3) {
            a[nxt] = *(const half8*)&A[(kt+1)*512];
            #pragma unroll
            for (int nn = 0; nn < 2; ++nn)
                b[nxt][nn] = *(const half8*)&Bp[nn*2048 + (kt+1)*512];
        }
        #pragma unroll
        for (int nn = 0; nn < 2; ++nn)
            acc[nn] = __builtin_amdgcn_mfma_f32_16x16x32_f16(a[cur], b[cur][nn], acc[nn], 0, 0, 0);
    }
}

// f32 -> f16 fragment-major panels + fused per-pair max row-norm^2 (sim bound)
__global__ __launch_bounds__(256) void convert_kernel(
    const float* __restrict__ Xin, const float* __restrict__ Xtg,
    _Float16* __restrict__ F, uint32_t* __restrict__ Ru)
{
    const int t = threadIdx.x;
    const int m = blockIdx.y;
    const float* X = m ? Xtg : Xin;
    const size_t e8 = (size_t)blockIdx.x * 256 + t;
    const size_t idx = e8 * 8;
    const int b = (int)(e8 >> 15);
    const int r = (int)((idx >> 7) & 2047);
    const int k = (int)(idx & 127);

    float4 v0 = *(const float4*)&X[idx];
    float4 v1 = *(const float4*)&X[idx + 4];
    float vv[8] = {v0.x, v0.y, v0.z, v0.w, v1.x, v1.y, v1.z, v1.w};
    _Float16 h8[8];
    float s = 0.f;
    #pragma unroll
    for (int j = 0; j < 8; ++j) {
        float f = fminf(fmaxf(vv[j], -60000.f), 60000.f);  // f16-range guard
        h8[j] = (_Float16)f;
        s += vv[j] * vv[j];
    }
    const int p = m * B_ + b;
    const size_t off = (size_t)p * (N_*D_)
        + (size_t)((r >> 4) * 4 + (k >> 5)) * 512
        + (size_t)((r & 15) + ((k >> 3) & 3) * 16) * 8;
    *(half8*)&F[off] = *(half8*)h8;

    // 16 consecutive lanes cover one row of 128 k
    s += __shfl_xor(s, 1); s += __shfl_xor(s, 2); s += __shfl_xor(s, 4); s += __shfl_xor(s, 8);
    s = fmaxf(s, __shfl_xor(s, 16)); s = fmaxf(s, __shfl_xor(s, 32));
    __shared__ float wm[4];
    if ((t & 63) == 0) wm[t >> 6] = s;
    __syncthreads();
    if (t == 0) {
        float mx = fmaxf(fmaxf(wm[0], wm[1]), fmaxf(wm[2], wm[3]));
        atomicMax(&Ru[p * 16], __float_as_uint(mx));   // positive: uint order == float order
    }
}

// Sampled (1/8) 8K-bin hist of POSITIVE sims over (0,R]: eighth-tile GEMM.
// Packed-u16 LDS, non-atomic replica flush. v<=0 skipped.
// Low 4 bits of blockIdx carry p -> pair pinned to one XCD L2.
__global__ __launch_bounds__(256) void hist_kernel(
    const _Float16* __restrict__ F, const uint32_t* __restrict__ Ru,
    uint32_t* __restrict__ rep)
{
    __shared__ uint32_t lh[NBINS / 2];   // 16 KB packed u16 pairs
    const int t = threadIdx.x;
    const int id = blockIdx.x;
    const int p = id & 15, g = id >> 4;

    for (int i = t; i < NBINS/2; i += 256) lh[i] = 0;
    __syncthreads();

    const _Float16* Fp = F + (size_t)p * (N_*D_);
    const float R = __uint_as_float(Ru[p * 16]);
    const float scl = (float)NBINS / R;

    for (int j = 0; j < TPG; ++j) {
        int rem = g * TPG + j, ti = 0;
        while (true) { int len = NT - ti; if (rem < len) break; rem -= len; ++ti; }
        const int tj = ti + rem;
        const uint32_t w = (ti == tj) ? 1u : 2u;

        f32x4 acc[2];
        gemm16_e(Fp, ti, tj, acc, t);
        #pragma unroll
        for (int nn = 0; nn < 2; ++nn)
            #pragma unroll
            for (int r = 0; r < 4; ++r) {
                float v = acc[nn][r];
                if (v > 0.f) {
                    int bin = (int)(v * scl);
                    if (bin >= NBINS) bin = NBINS - 1;
                    atomicAdd(&lh[bin >> 1], w << ((bin & 1) * 16));
                }
            }
    }
    __syncthreads();
    uint32_t* dst = rep + ((size_t)p * GH + g) * (NBINS/2);
    for (int i = t; i < NBINS/2; i += 256) dst[i] = lh[i];
}

// parallel replica reduce: 256 blocks (16 pairs x 16 chunks), coalesced.
__global__ __launch_bounds__(256) void reduce_kernel(
    const uint32_t* __restrict__ rep, uint32_t* __restrict__ h32)
{
    const int id = blockIdx.x;
    const int p = id & 15, chunk = id >> 4;
    const int t = threadIdx.x;
    const int wd = chunk * 256 + t;                 // packed-word idx 0..4095
    const uint32_t* base = rep + (size_t)p * GH * (NBINS/2) + wd;
    uint32_t lo = 0, hi = 0;
    #pragma unroll
    for (int g = 0; g < GH; ++g) {
        uint32_t x = base[(size_t)g * (NBINS/2)];
        lo += x & 0xffffu; hi += x >> 16;
    }
    uint32_t* hp = h32 + (size_t)p * NBINS;
    hp[wd*2]     = lo;
    hp[wd*2 + 1] = hi;
}

// descending scan of u32 hist with rank k/8 (1/8 sample): thr = bin lower edge
__global__ __launch_bounds__(256) void select_kernel(
    const uint32_t* __restrict__ h32, const int* __restrict__ kptr,
    const uint32_t* __restrict__ Ru, float* __restrict__ thr)
{
    __shared__ uint32_t csum[256], cpre[256];
    const int p = blockIdx.x, t = threadIdx.x;
    const uint32_t* h = h32 + (size_t)p * NBINS;
    const uint32_t k0 = ((uint32_t)kptr[0] + 4u) >> 3;   // sampled rank
    const float R = __uint_as_float(Ru[p * 16]);
    const float binw = R / (float)NBINS;

    const int top = NBINS - 1 - t * 32;
    uint32_t s = 0;
    #pragma unroll
    for (int j = 0; j < 32; ++j) s += h[top - j];
    csum[t] = s;
    __syncthreads();
    if (t == 0) { uint32_t run = 0; for (int i = 0; i < 256; ++i) { cpre[i] = run; run += csum[i]; } }
    __syncthreads();
    const uint32_t above = cpre[t];
    if (above < k0 && above + s >= k0) {
        uint32_t cum = above;
        for (int j = 0; j < 32; ++j) {
            int bin = top - j;
            cum += h[bin];
            if (cum >= k0) { thr[p] = (float)bin * binw; break; }   // lower edge
        }
    }
}

// masked MSE: merged dual-side GEMM pipeline (8 unrolled steps, shared operand
// double-buffer, dual accumulators) -> continuous load stream, no inter-call
// stall. Low 3 bits of blockIdx carry p -> both panels (2MB) on one XCD L2.
__global__ __launch_bounds__(256) void mse_kernel(
    const _Float16* __restrict__ F, const float* __restrict__ thr,
    double* __restrict__ accum)
{
    const int t = threadIdx.x;
    const int id = blockIdx.x;
    const int p = id & 7, tile = id >> 3;

    int rem = tile, ti = 0;
    while (true) { int len = NT - ti; if (rem < len) break; rem -= len; ++ti; }
    const int tj = ti + rem;
    const uint32_t w = (ti == tj) ? 1u : 2u;

    const int lane = t & 63;
    const int wv = t >> 6, wr = wv >> 1, wc = wv & 1;
    const _Float16* FI = F + (size_t)p * (N_*D_);
    const _Float16* FT = F + (size_t)(B_ + p) * (N_*D_);
    const _Float16* AI = FI + (size_t)(ti*8 + wr*4)*2048 + (size_t)lane*8;
    const _Float16* BI = FI + (size_t)(tj*8 + wc*4)*2048 + (size_t)lane*8;
    const _Float16* AT = FT + (size_t)(ti*8 + wr*4)*2048 + (size_t)lane*8;
    const _Float16* BT = FT + (size_t)(tj*8 + wc*4)*2048 + (size_t)lane*8;

    f32x4 accI[4][4], accT[4][4];
    #pragma unroll
    for (int mm = 0; mm < 4; ++mm)
        #pragma unroll
        for (int nn = 0; nn < 4; ++nn) {
            accI[mm][nn] = f32x4{0.f, 0.f, 0.f, 0.f};
            accT[mm][nn] = f32x4{0.f, 0.f, 0.f, 0.f};
        }

    half8 a[2][4], b[2][4];
    #pragma unroll
    for (int mm = 0; mm < 4; ++mm) {
        a[0][mm] = *(const half8*)&AI[mm*2048];
        b[0][mm] = *(const half8*)&BI[mm*2048];
    }

    #pragma unroll
    for (int s = 0; s < 8; ++s) {
        const int cur = s & 1, nxt = cur ^ 1;
        if (s < 7) {
            const int s2 = s + 1, kt2 = s2 & 3;
            const _Float16* A2 = (s2 < 4) ? AI : AT;
            const _Float16* B2 = (s2 < 4) ? BI : BT;
            #pragma unroll
            for (int mm = 0; mm < 4; ++mm) {
                a[nxt][mm] = *(const half8*)&A2[mm*2048 + kt2*512];
                b[nxt][mm] = *(const half8*)&B2[mm*2048 + kt2*512];
            }
        }
        if (s < 4) {
            #pragma unroll
            for (int mm = 0; mm < 4; ++mm)
                #pragma unroll
                for (int nn = 0; nn < 4; ++nn)
                    accI[mm][nn] = __builtin_amdgcn_mfma_f32_16x16x32_f16(a[cur][mm], b[cur][nn], accI[mm][nn], 0, 0, 0);
        } else {
            #pragma unroll
            for (int mm = 0; mm < 4; ++mm)
                #pragma unroll
                for (int nn = 0; nn < 4; ++nn)
                    accT[mm][nn] = __builtin_amdgcn_mfma_f32_16x16x32_f16(a[cur][mm], b[cur][nn], accT[mm][nn], 0, 0, 0);
        }
    }

    const float thrI = thr[p], thrT = thr[B_ + p];
    float local = 0.f;
    #pragma unroll
    for (int mm = 0; mm < 4; ++mm)
        #pragma unroll
        for (int nn = 0; nn < 4; ++nn)
            #pragma unroll
            for (int r = 0; r < 4; ++r) {
                float vI = accI[mm][nn][r], aI = (vI >= thrI) ? vI : 0.f;
                float vT = accT[mm][nn][r], aT = (vT >= thrT) ? vT : 0.f;
                float d = aI - aT;
                local += d * d;
            }
    local *= (float)w;
    #pragma unroll
    for (int off = 32; off; off >>= 1) local += __shfl_down(local, off);
    __shared__ float wsum[4];
    if ((t & 63) == 0) wsum[t >> 6] = local;
    __syncthreads();
    if (t == 0) {
        double s2 = (double)wsum[0] + (double)wsum[1] + (double)wsum[2] + (double)wsum[3];
        atomicAdd(accum, s2);
    }
}

__global__ void finalize_kernel(const double* __restrict__ accum, float* __restrict__ out) {
    out[0] = (float)(accum[0] / ((double)B_ * (double)N_ * (double)N_));
}

extern "C" void kernel_launch(void* const* d_in, const int* in_sizes, int n_in,
                              void* d_out, int out_size, void* d_ws, size_t ws_size,
                              hipStream_t stream)
{
    const float* Xin = (const float*)d_in[0];
    const float* Xtg = (const float*)d_in[1];
    const int*  kptr = (const int*)d_in[3];
    float* out = (float*)d_out;

    char* ws = (char*)d_ws;
    double*    accum = (double*)   (ws + OFF_ACCUM);
    uint32_t*  Ru    = (uint32_t*) (ws + OFF_RU);
    float*     thr   = (float*)    (ws + OFF_THR);
    uint32_t*  h32   = (uint32_t*) (ws + OFF_H32);
    uint32_t*  rep   = (uint32_t*) (ws + OFF_REP);
    _Float16*  F     = (_Float16*) (ws + OFF_F);
    if (ws_size < NEED) return;

    hipMemsetAsync(d_ws, 0, OFF_H32, stream);   // accum, Ru, thr (h32/rep/F overwritten)

    dim3 blk(256);
    convert_kernel<<<dim3(1024, 2), blk, 0, stream>>>(Xin, Xtg, F, Ru);
    hist_kernel<<<dim3(GH * 16), blk, 0, stream>>>(F, Ru, rep);
    reduce_kernel<<<dim3(16 * 16), blk, 0, stream>>>(rep, h32);
    select_kernel<<<dim3(16), blk, 0, stream>>>(h32, kptr, Ru, thr);
    mse_kernel<<<dim3(NPAIRS * 8), blk, 0, stream>>>(F, thr, accum);
    finalize_kernel<<<1, 1, 0, stream>>>(accum, out);
}